// Round 8
// baseline (183.970 us; speedup 1.0000x reference)
//
#include <hip/hip_runtime.h>
#include <hip/hip_bf16.h>

// Problem constants (reference: B=2, L=2048, D=1024, H=16, HD=64, LD=256)
#define BB   2
#define LL   2048
#define DD   1024
#define HH   16
#define HDD  64
#define LDIM 256
#define MTOT (BB * LL)   // 4096 rows for all projection GEMMs

using short8  = __attribute__((ext_vector_type(8))) short;  // 8 bf16 (4 VGPRs)
using floatx4 = __attribute__((ext_vector_type(4))) float;  // MFMA C/D frag

static __device__ __forceinline__ unsigned short f2bf(float x) {
  __hip_bfloat16 h = __float2bfloat16(x);
  return *reinterpret_cast<unsigned short*>(&h);
}
static __device__ __forceinline__ unsigned int pk_bf16(float a, float b) {
  return (unsigned int)f2bf(a) | ((unsigned int)f2bf(b) << 16);
}
// async 16B/lane global->LDS; lds base wave-uniform, HW adds lane*16
static __device__ __forceinline__ void load_lds16(const unsigned short* g,
                                                  unsigned short* l) {
  __builtin_amdgcn_global_load_lds(
      (const __attribute__((address_space(1))) unsigned int*)g,
      (__attribute__((address_space(3))) unsigned int*)l, 16, 0, 0);
}
template <int N>
static __device__ __forceinline__ void waitcnt_vm() {
  if constexpr (N == 0) asm volatile("s_waitcnt vmcnt(0)" ::: "memory");
  else if constexpr (N == 4) asm volatile("s_waitcnt vmcnt(4)" ::: "memory");
  else if constexpr (N == 8) asm volatile("s_waitcnt vmcnt(8)" ::: "memory");
}

// ---------------------------------------------------------------------------
// cast fp32 -> bf16, 4 elems/thread
// ---------------------------------------------------------------------------
__global__ __launch_bounds__(256) void cast_bf16(const float* __restrict__ in,
                                                 unsigned short* __restrict__ out,
                                                 int n4) {
  const int i = (blockIdx.x * 256 + threadIdx.x);
  if (i < n4) {
    float4 v = ((const float4*)in)[i];
    ushort4 o;
    o.x = f2bf(v.x); o.y = f2bf(v.y); o.z = f2bf(v.z); o.w = f2bf(v.w);
    ((ushort4*)out)[i] = o;
  }
}

// ---------------------------------------------------------------------------
// fused transpose+cast for all 5 weights: fp32 [R][C] -> bf16 [C][R].
// grid (32,32,5), block (32,8); out-of-range tiles exit early.
// ---------------------------------------------------------------------------
__global__ __launch_bounds__(256) void transpose_cast5(
    const float* __restrict__ Wq, const float* __restrict__ Wkv,
    const float* __restrict__ Wku, const float* __restrict__ Wvu,
    const float* __restrict__ Wo,
    unsigned short* __restrict__ WqT, unsigned short* __restrict__ WkvT,
    unsigned short* __restrict__ WkuT, unsigned short* __restrict__ WvuT,
    unsigned short* __restrict__ WoT) {
  const float* src; unsigned short* dst; int R, C;
  switch (blockIdx.z) {
    case 0:  src = Wq;  dst = WqT;  R = 1024; C = 1024; break;
    case 1:  src = Wkv; dst = WkvT; R = 1024; C = 256;  break;
    case 2:  src = Wku; dst = WkuT; R = 256;  C = 1024; break;
    case 3:  src = Wvu; dst = WvuT; R = 256;  C = 1024; break;
    default: src = Wo;  dst = WoT;  R = 1024; C = 1024; break;
  }
  if ((int)blockIdx.x * 32 >= C || (int)blockIdx.y * 32 >= R) return;

  __shared__ float tile[32][33];
  const int tx = threadIdx.x, ty = threadIdx.y;
#pragma unroll
  for (int i = 0; i < 4; ++i) {
    const int r = blockIdx.y * 32 + ty + i * 8;
    tile[ty + i * 8][tx] = src[(size_t)r * C + blockIdx.x * 32 + tx];
  }
  __syncthreads();
#pragma unroll
  for (int i = 0; i < 4; ++i) {
    const int c = blockIdx.x * 32 + ty + i * 8;
    dst[(size_t)c * R + blockIdx.y * 32 + tx] = f2bf(tile[tx][ty + i * 8]);
  }
}

// ---------------------------------------------------------------------------
// bf16 MFMA GEMM, pipelined K-loop: C = A[M,K] * Bt[N,K]^T.
// Grid (x = M-tiles [fastest], y = N-tiles) for XCD L2 locality on A.
// Tile BMT x BNT, BK=32, 256 thr = 4 waves (2x2). Double-buffered
// global_load_lds staging: prefetch k+1 BEFORE waiting, vmcnt(NLD) + raw
// s_barrier (never vmcnt(0) mid-loop).
// KIND 0: fp32 C0[M][N]
// KIND 1: C0 = Qh bf16 [B][H][L][64], C1 = latent bf16 [M][256]
// KIND 2: C0 = Kh bf16 [B][H][L][64], C1 = Vt bf16 [B][H][64][L] (packed st.)
// ---------------------------------------------------------------------------
template <int KIND, int BMT, int BNT>
__global__ __launch_bounds__(256) void gemm2(const unsigned short* __restrict__ A,
                                             const unsigned short* __restrict__ Bt0,
                                             const unsigned short* __restrict__ Bt1,
                                             void* __restrict__ C0,
                                             void* __restrict__ C1,
                                             int M, int N, int K, int nsplit) {
  constexpr int IM = BMT / 32, JN = BNT / 32;
  constexpr int NLD = BMT / 64 + BNT / 64;   // per-wave loads per k-tile
  __shared__ __align__(16) unsigned short As[2 * BMT * 32];
  __shared__ __align__(16) unsigned short Bs[2 * BNT * 32];

  const int tid  = threadIdx.x;
  const int w    = tid >> 6;
  const int lane = tid & 63;
  const int lo   = lane & 15;
  const int g    = lane >> 4;
  const int wr   = w >> 1, wc = w & 1;
  const int row0  = blockIdx.x * BMT;   // M on x (fastest) for XCD locality
  const int col0g = blockIdx.y * BNT;
  const bool second = (col0g >= nsplit);            // block-uniform
  const unsigned short* Btp = second ? Bt1 : Bt0;
  const int col0 = second ? col0g - nsplit : col0g;

  floatx4 acc[IM][JN];
#pragma unroll
  for (int i = 0; i < IM; ++i)
#pragma unroll
    for (int j = 0; j < JN; ++j) acc[i][j] = (floatx4){0.f, 0.f, 0.f, 0.f};

  const int sr = tid >> 2;   // staging row (64 rows per inst)
  const int sc = tid & 3;    // staging k-chunk

  auto stage = [&](int buf, int k0) {
#pragma unroll
    for (int inst = 0; inst < BMT / 64; ++inst) {
      const int r  = inst * 64 + sr;
      const int cs = sc ^ ((r >> 1) & 3);
      load_lds16(A + (size_t)(row0 + r) * K + k0 + cs * 8,
                 As + buf * (BMT * 32) + inst * 2048 + w * 512);
    }
#pragma unroll
    for (int inst = 0; inst < BNT / 64; ++inst) {
      const int r  = inst * 64 + sr;
      const int cs = sc ^ ((r >> 1) & 3);
      load_lds16(Btp + (size_t)(col0 + r) * K + k0 + cs * 8,
                 Bs + buf * (BNT * 32) + inst * 2048 + w * 512);
    }
  };

  const int nk = K / 32;
  stage(0, 0);                          // prologue
  for (int it = 0; it < nk; ++it) {
    const int cur = it & 1;
    if (it + 1 < nk) {
      stage(cur ^ 1, (it + 1) * 32);    // prefetch BEFORE waiting
      waitcnt_vm<NLD>();                // only tile-it's loads
    } else {
      waitcnt_vm<0>();
    }
    asm volatile("s_barrier" ::: "memory");

    const unsigned short* Ac = As + cur * (BMT * 32);
    const unsigned short* Bc = Bs + cur * (BNT * 32);
    short8 af[IM], bf[JN];
#pragma unroll
    for (int i = 0; i < IM; ++i) {
      const int rm = (BMT / 2) * wr + 16 * i + lo;
      af[i] = *(const short8*)(Ac + rm * 32 + ((g ^ ((rm >> 1) & 3)) * 8));
    }
#pragma unroll
    for (int j = 0; j < JN; ++j) {
      const int rn = (BNT / 2) * wc + 16 * j + lo;
      bf[j] = *(const short8*)(Bc + rn * 32 + ((g ^ ((rn >> 1) & 3)) * 8));
    }
#pragma unroll
    for (int i = 0; i < IM; ++i)
#pragma unroll
      for (int j = 0; j < JN; ++j)
        acc[i][j] = __builtin_amdgcn_mfma_f32_16x16x32_bf16(af[i], bf[j], acc[i][j], 0, 0, 0);

    asm volatile("s_barrier" ::: "memory");  // cur buf free for it+2 prefetch
  }

#pragma unroll
  for (int i = 0; i < IM; ++i) {
    const int mbase = row0 + (BMT / 2) * wr + 16 * i + g * 4;
#pragma unroll
    for (int j = 0; j < JN; ++j) {
      const int nl = col0 + (BNT / 2) * wc + 16 * j + lo;
      const int bq = mbase >> 11, hh = nl >> 6, d = nl & 63;
      if (KIND == 2 && second) {
        const int l = mbase & 2047;
        uint2 o;
        o.x = pk_bf16(acc[i][j][0], acc[i][j][1]);
        o.y = pk_bf16(acc[i][j][2], acc[i][j][3]);
        *(uint2*)(&((unsigned short*)C1)[((size_t)(bq * HH + hh) * HDD + d) * LL + l]) = o;
      } else {
#pragma unroll
        for (int r = 0; r < 4; ++r) {
          const float v = acc[i][j][r];
          const int mm = mbase + r;
          const int l = mm & 2047;
          if (KIND == 0) {
            ((float*)C0)[(size_t)mm * N + nl] = v;
          } else if (KIND == 1) {
            if (!second)
              ((unsigned short*)C0)[((size_t)(bq * HH + hh) * LL + l) * HDD + d] = f2bf(v);
            else
              ((unsigned short*)C1)[(size_t)mm * LDIM + nl] = f2bf(v);
          } else {
            ((unsigned short*)C0)[((size_t)(bq * HH + hh) * LL + l) * HDD + d] = f2bf(v);
          }
        }
      }
    }
  }
}

// ---------------------------------------------------------------------------
// MFMA causal flash attention v7: split-K with additive merge.
// Fixed-max softmax => partial (O, l) over disjoint k-ranges merge by
// ADDITION (no max rescale). Per (b,h): 32 blocks:
//   j <  16: piece A = q-tile j, k-tiles 0..j (direct y write, j+1 iters)
//            piece B = q-tile 31-j, k-tiles 16..31-j (partial, 16-j iters)
//   j >= 16: q-tile j, k-tiles 0..15 (partial, 16 iters, unmasked)
// => every block 16-17 iters (balanced), 1024 blocks = 4/CU (LDS-limited,
// fully resident). Partials fp32 O[q][d] + l in ws; merge kernel sums.
// K/V double-buffered via global_load_lds + vmcnt(4) + raw s_barrier.
// ---------------------------------------------------------------------------
#define SC2 0.18033688011112042f   // 0.125 * log2(e)

__global__ __launch_bounds__(256) void flash_mfma7(const unsigned short* __restrict__ Qh,
                                                   const unsigned short* __restrict__ Kh,
                                                   const unsigned short* __restrict__ Vt,
                                                   unsigned short* __restrict__ y,
                                                   float* __restrict__ Opart,
                                                   float* __restrict__ lpart) {
  const int w    = threadIdx.x >> 6;
  const int lane = threadIdx.x & 63;
  const int lo   = lane & 15;
  const int g    = lane >> 4;
  const int h    = blockIdx.x;
  const int b    = blockIdx.y;
  const int j    = blockIdx.z;     // 0..31

  __shared__ __align__(16) unsigned short Ks[2 * 64 * 64];  // [buf][k][d] swiz
  __shared__ __align__(16) unsigned short Vs[2 * 64 * 64];  // [buf][d][k] swiz
  __shared__ __align__(16) unsigned short Pq[4][16 * 64];   // per-wave [q][k]

  const int    bh = b * HH + h;
  const unsigned short* Qp = Qh + (size_t)bh * LL * HDD;
  const unsigned short* Kp = Kh + (size_t)bh * LL * HDD;
  const unsigned short* Vp = Vt + (size_t)bh * HDD * LL;
  unsigned short* Pw = Pq[w];

  const int srow = lane >> 3;   // staging: 8 rows/inst
  const int sch  = lane & 7;

  auto stage = [&](int buf, int k0) {
#pragma unroll
    for (int t = 0; t < 2; ++t) {
      const int rbase = w * 16 + t * 8;
      const int row   = rbase + srow;
      const int cs    = sch ^ (row & 7);
      load_lds16(Kp + (size_t)(k0 + row) * HDD + cs * 8, Ks + buf * 4096 + rbase * 64);
      load_lds16(Vp + (size_t)row * LL + k0 + cs * 8,    Vs + buf * 4096 + rbase * 64);
    }
  };

  // run one piece: q-tile qt against k-tiles it0..it1 (inclusive).
  // direct=true -> normalize+write y; else -> store fp32 partial at slot.
  auto run_piece = [&](int qt, int it0, int it1, int piece, bool direct) {
    const int qw = qt * 64 + w * 16;
    short8 qf0 = *(const short8*)(Qp + (size_t)(qw + lo) * HDD + g * 8);
    short8 qf1 = *(const short8*)(Qp + (size_t)(qw + lo) * HDD + 32 + g * 8);

    floatx4 ot[4];
#pragma unroll
    for (int ds = 0; ds < 4; ++ds) ot[ds] = (floatx4){0.f, 0.f, 0.f, 0.f};
    float lsum = 0.f;

    stage(0, it0 * 64);
    for (int it = it0; it <= it1; ++it) {
      const int cur = (it - it0) & 1;
      const int k0  = it * 64;
      if (it < it1) {
        stage(cur ^ 1, k0 + 64);
        waitcnt_vm<4>();
      } else {
        waitcnt_vm<0>();
      }
      asm volatile("s_barrier" ::: "memory");

      const unsigned short* Kc = Ks + cur * 4096;
      const unsigned short* Vc = Vs + cur * 4096;

      // ---- St(64k x 16q) = K Q^T ----
      floatx4 st[4];
#pragma unroll
      for (int ks = 0; ks < 4; ++ks) {
        const int rm = ks * 16 + lo;
        short8 a0 = *(const short8*)(Kc + rm * 64 + ((g ^ (rm & 7)) * 8));
        short8 a1 = *(const short8*)(Kc + rm * 64 + (((4 + g) ^ (rm & 7)) * 8));
        floatx4 s = (floatx4){0.f, 0.f, 0.f, 0.f};
        s = __builtin_amdgcn_mfma_f32_16x16x32_bf16(a0, qf0, s, 0, 0, 0);
        s = __builtin_amdgcn_mfma_f32_16x16x32_bf16(a1, qf1, s, 0, 0, 0);
        st[ks] = s;
      }
      // ---- fixed-max softmax + P^T -> per-wave LDS [q][k] ----
      if (it != qt) {
#pragma unroll
        for (int ks = 0; ks < 4; ++ks) {
          float p[4];
#pragma unroll
          for (int r = 0; r < 4; ++r) {
            p[r] = __builtin_amdgcn_exp2f(st[ks][r] * SC2);
            lsum += p[r];
          }
          uint2 w2;
          w2.x = pk_bf16(p[0], p[1]);
          w2.y = pk_bf16(p[2], p[3]);
          *(uint2*)(Pw + lo * 64 + (((ks * 2 + (g >> 1)) ^ (lo & 7)) * 8) + (g & 1) * 4) = w2;
        }
      } else {   // diagonal tile: causal mask
        const int qq = qw + lo;
#pragma unroll
        for (int ks = 0; ks < 4; ++ks) {
          float p[4];
#pragma unroll
          for (int r = 0; r < 4; ++r) {
            const int kk = k0 + ks * 16 + g * 4 + r;
            const float e = __builtin_amdgcn_exp2f(st[ks][r] * SC2);
            p[r] = (kk <= qq) ? e : 0.f;
            lsum += p[r];
          }
          uint2 w2;
          w2.x = pk_bf16(p[0], p[1]);
          w2.y = pk_bf16(p[2], p[3]);
          *(uint2*)(Pw + lo * 64 + (((ks * 2 + (g >> 1)) ^ (lo & 7)) * 8) + (g & 1) * 4) = w2;
        }
      }
      // ---- O^T(64d x 16q) += V^T P^T ----
      short8 pf0 = *(const short8*)(Pw + lo * 64 + ((g ^ (lo & 7)) * 8));
      short8 pf1 = *(const short8*)(Pw + lo * 64 + (((4 + g) ^ (lo & 7)) * 8));
#pragma unroll
      for (int ds = 0; ds < 4; ++ds) {
        const int rm = ds * 16 + lo;
        short8 v0 = *(const short8*)(Vc + rm * 64 + ((g ^ (rm & 7)) * 8));
        short8 v1 = *(const short8*)(Vc + rm * 64 + (((4 + g) ^ (rm & 7)) * 8));
        ot[ds] = __builtin_amdgcn_mfma_f32_16x16x32_bf16(v0, pf0, ot[ds], 0, 0, 0);
        ot[ds] = __builtin_amdgcn_mfma_f32_16x16x32_bf16(v1, pf1, ot[ds], 0, 0, 0);
      }
      asm volatile("s_barrier" ::: "memory");  // cur buf free for next prefetch
    }

    // reduce l over g-groups (q = qw + lo for all of them)
    float s = lsum;
    s += __shfl_xor(s, 16);
    s += __shfl_xor(s, 32);

    if (direct) {
      const float inv = 1.0f / s;
#pragma unroll
      for (int ds = 0; ds < 4; ++ds) {
        uint2 o;
        o.x = pk_bf16(ot[ds][0] * inv, ot[ds][1] * inv);
        o.y = pk_bf16(ot[ds][2] * inv, ot[ds][3] * inv);
        *(uint2*)(y + (size_t)(b * LL + qw + lo) * (HH * HDD) + h * HDD + ds * 16 + g * 4) = o;
      }
    } else {
      // slot for q-tiles >= 16: s = (qt-16)*2 + piece; rows [q] of 64 floats
      const int slot = bh * 32 + (qt - 16) * 2 + piece;
      float* Orow = Opart + ((size_t)slot * 64 + w * 16 + lo) * 64;
#pragma unroll
      for (int ds = 0; ds < 4; ++ds) {
        float4 f = make_float4(ot[ds][0], ot[ds][1], ot[ds][2], ot[ds][3]);
        *(float4*)(Orow + ds * 16 + g * 4) = f;
      }
      if (g == 0) lpart[(size_t)slot * 64 + w * 16 + lo] = s;
    }
  };

  if (j < 16) {
    run_piece(j, 0, j, 0, true);                 // full light q-tile -> y
    run_piece(31 - j, 16, 31 - j, 1, false);     // tail piece of heavy q-tile
  } else {
    run_piece(j, 0, 15, 0, false);               // head piece of heavy q-tile
  }
}

// ---------------------------------------------------------------------------
// merge: for q-tiles 16..31, y = (O_p0 + O_p1) / (l0 + l1), bf16.
// grid (16, H, B), 256 thr; thread -> (q = t>>2, d-block = (t&3)*16).
// ---------------------------------------------------------------------------
__global__ __launch_bounds__(256) void merge_flash(const float* __restrict__ Opart,
                                                   const float* __restrict__ lpart,
                                                   unsigned short* __restrict__ y) {
  const int qt = 16 + blockIdx.x;
  const int h  = blockIdx.y;
  const int b  = blockIdx.z;
  const int bh = b * HH + h;
  const int t  = threadIdx.x;
  const int q  = t >> 2;
  const int dg = (t & 3) * 16;

  const int s0 = bh * 32 + (qt - 16) * 2;
  const float l = lpart[(size_t)s0 * 64 + q] + lpart[(size_t)(s0 + 1) * 64 + q];
  const float inv = 1.0f / l;

  const float* O0 = Opart + ((size_t)s0 * 64 + q) * 64 + dg;
  const float* O1 = Opart + ((size_t)(s0 + 1) * 64 + q) * 64 + dg;
  unsigned short* yp = y + (size_t)(b * LL + qt * 64 + q) * (HH * HDD) + h * HDD + dg;

#pragma unroll
  for (int i = 0; i < 4; ++i) {
    float4 a = ((const float4*)O0)[i];
    float4 c = ((const float4*)O1)[i];
    uint2 o;
    o.x = pk_bf16((a.x + c.x) * inv, (a.y + c.y) * inv);
    o.y = pk_bf16((a.z + c.z) * inv, (a.w + c.w) * inv);
    *(uint2*)(yp + i * 4) = o;
  }
}

// ---------------------------------------------------------------------------
// Launch
// ---------------------------------------------------------------------------
extern "C" void kernel_launch(void* const* d_in, const int* in_sizes, int n_in,
                              void* d_out, int out_size, void* d_ws, size_t ws_size,
                              hipStream_t stream) {
  const float* x   = (const float*)d_in[0];  // [4096][1024]
  const float* Wq  = (const float*)d_in[1];  // [1024][1024]
  const float* Wkv = (const float*)d_in[2];  // [1024][256]
  const float* Wku = (const float*)d_in[3];  // [256][1024]
  const float* Wvu = (const float*)d_in[4];  // [256][1024]
  const float* Wo  = (const float*)d_in[5];  // [1024][1024]
  float* out = (float*)d_out;                // [4096][1024] fp32

  // workspace
  unsigned short* xb     = (unsigned short*)d_ws;          // 4096x1024 bf16
  unsigned short* WqT    = xb + (size_t)MTOT * DD;         // 1024x1024 [N][K]
  unsigned short* WkvT   = WqT + 1024 * 1024;              // 256x1024
  unsigned short* WkuT   = WkvT + 256 * 1024;              // 1024x256
  unsigned short* WvuT   = WkuT + 1024 * 256;              // 1024x256
  unsigned short* WoT    = WvuT + 1024 * 256;              // 1024x1024
  unsigned short* latent = WoT + 1024 * 1024;              // 4096x256
  unsigned short* Qh     = latent + (size_t)MTOT * LDIM;   // 4096x1024
  unsigned short* Kh     = Qh + (size_t)MTOT * DD;
  unsigned short* Vt     = Kh + (size_t)MTOT * DD;
  unsigned short* y      = Vt + (size_t)MTOT * DD;
  float* Opart = (float*)(y + (size_t)MTOT * DD);          // 32bh x 32slot x 64q x 64d
  float* lpart = Opart + (size_t)32 * 32 * 64 * 64;        // 32bh x 32slot x 64q

  // prep
  cast_bf16<<<dim3(MTOT * DD / 1024), dim3(256), 0, stream>>>(x, xb, MTOT * DD / 4);
  transpose_cast5<<<dim3(32, 32, 5), dim3(32, 8), 0, stream>>>(
      Wq, Wkv, Wku, Wvu, Wo, WqT, WkvT, WkuT, WvuT, WoT);

  // fused Q + latent:  [4096,1024] x [1024, 1024+256]   (M-tiles on x)
  gemm2<1, 128, 128><<<dim3(MTOT / 128, 1280 / 128), dim3(256), 0, stream>>>(
      xb, WqT, WkvT, Qh, latent, MTOT, 1280, DD, 1024);
  // fused K + V:       [4096,256] x [256, 1024+1024]
  gemm2<2, 128, 128><<<dim3(MTOT / 128, 2048 / 128), dim3(256), 0, stream>>>(
      latent, WkuT, WvuT, Kh, Vt, MTOT, 2048, LDIM, 1024);

  // attention: split-K flash (h fastest for XCD L2 locality) + merge
  flash_mfma7<<<dim3(HH, BB, 32), dim3(256), 0, stream>>>(Qh, Kh, Vt, y, Opart, lpart);
  merge_flash<<<dim3(16, HH, BB), dim3(256), 0, stream>>>(Opart, lpart, y);

  // output projection (fp32 out)
  gemm2<0, 128, 128><<<dim3(MTOT / 128, DD / 128), dim3(256), 0, stream>>>(
      y, WoT, nullptr, out, nullptr, MTOT, DD, DD, DD);
}

// Round 9
// 170.315 us; speedup vs baseline: 1.0802x; 1.0802x over previous
//
#include <hip/hip_runtime.h>
#include <hip/hip_bf16.h>

// Problem constants (reference: B=2, L=2048, D=1024, H=16, HD=64, LD=256)
#define BB   2
#define LL   2048
#define DD   1024
#define HH   16
#define HDD  64
#define LDIM 256
#define MTOT (BB * LL)   // 4096 rows for all projection GEMMs

using short8  = __attribute__((ext_vector_type(8))) short;  // 8 bf16 (4 VGPRs)
using floatx4 = __attribute__((ext_vector_type(4))) float;  // MFMA C/D frag

static __device__ __forceinline__ unsigned short f2bf(float x) {
  __hip_bfloat16 h = __float2bfloat16(x);
  return *reinterpret_cast<unsigned short*>(&h);
}
static __device__ __forceinline__ unsigned int pk_bf16(float a, float b) {
  return (unsigned int)f2bf(a) | ((unsigned int)f2bf(b) << 16);
}
// async 16B/lane global->LDS; lds base wave-uniform, HW adds lane*16
static __device__ __forceinline__ void load_lds16(const unsigned short* g,
                                                  unsigned short* l) {
  __builtin_amdgcn_global_load_lds(
      (const __attribute__((address_space(1))) unsigned int*)g,
      (__attribute__((address_space(3))) unsigned int*)l, 16, 0, 0);
}
template <int N>
static __device__ __forceinline__ void waitcnt_vm() {
  if constexpr (N == 0) asm volatile("s_waitcnt vmcnt(0)" ::: "memory");
  else if constexpr (N == 3) asm volatile("s_waitcnt vmcnt(3)" ::: "memory");
  else if constexpr (N == 4) asm volatile("s_waitcnt vmcnt(4)" ::: "memory");
  else if constexpr (N == 8) asm volatile("s_waitcnt vmcnt(8)" ::: "memory");
}

// ---------------------------------------------------------------------------
// cast fp32 -> bf16, 4 elems/thread
// ---------------------------------------------------------------------------
__global__ __launch_bounds__(256) void cast_bf16(const float* __restrict__ in,
                                                 unsigned short* __restrict__ out,
                                                 int n4) {
  const int i = (blockIdx.x * 256 + threadIdx.x);
  if (i < n4) {
    float4 v = ((const float4*)in)[i];
    ushort4 o;
    o.x = f2bf(v.x); o.y = f2bf(v.y); o.z = f2bf(v.z); o.w = f2bf(v.w);
    ((ushort4*)out)[i] = o;
  }
}

// ---------------------------------------------------------------------------
// fused transpose+cast for all 5 weights: fp32 [R][C] -> bf16 [C][R].
// grid (32,32,5), block (32,8); out-of-range tiles exit early.
// ---------------------------------------------------------------------------
__global__ __launch_bounds__(256) void transpose_cast5(
    const float* __restrict__ Wq, const float* __restrict__ Wkv,
    const float* __restrict__ Wku, const float* __restrict__ Wvu,
    const float* __restrict__ Wo,
    unsigned short* __restrict__ WqT, unsigned short* __restrict__ WkvT,
    unsigned short* __restrict__ WkuT, unsigned short* __restrict__ WvuT,
    unsigned short* __restrict__ WoT) {
  const float* src; unsigned short* dst; int R, C;
  switch (blockIdx.z) {
    case 0:  src = Wq;  dst = WqT;  R = 1024; C = 1024; break;
    case 1:  src = Wkv; dst = WkvT; R = 1024; C = 256;  break;
    case 2:  src = Wku; dst = WkuT; R = 256;  C = 1024; break;
    case 3:  src = Wvu; dst = WvuT; R = 256;  C = 1024; break;
    default: src = Wo;  dst = WoT;  R = 1024; C = 1024; break;
  }
  if ((int)blockIdx.x * 32 >= C || (int)blockIdx.y * 32 >= R) return;

  __shared__ float tile[32][33];
  const int tx = threadIdx.x, ty = threadIdx.y;
#pragma unroll
  for (int i = 0; i < 4; ++i) {
    const int r = blockIdx.y * 32 + ty + i * 8;
    tile[ty + i * 8][tx] = src[(size_t)r * C + blockIdx.x * 32 + tx];
  }
  __syncthreads();
#pragma unroll
  for (int i = 0; i < 4; ++i) {
    const int c = blockIdx.x * 32 + ty + i * 8;
    dst[(size_t)c * R + blockIdx.y * 32 + tx] = f2bf(tile[tx][ty + i * 8]);
  }
}

// ---------------------------------------------------------------------------
// bf16 MFMA GEMM, pipelined K-loop: C = A[M,K] * Bt[N,K]^T.
// Grid (x = M-tiles [fastest], y = N-tiles) for XCD L2 locality on A.
// Tile BMT x BNT, BK=32, 256 thr = 4 waves (2x2). Double-buffered
// global_load_lds staging: prefetch k+1 BEFORE waiting, vmcnt(NLD) + raw
// s_barrier (never vmcnt(0) mid-loop).
// KIND 0: fp32 C0[M][N]
// KIND 1: C0 = Qh bf16 [B][H][L][64], C1 = latent bf16 [M][256]
// KIND 2: C0 = Kh bf16 [B][H][L][64], C1 = Vt bf16 [B][H][64][L] (packed st.)
// ---------------------------------------------------------------------------
template <int KIND, int BMT, int BNT>
__global__ __launch_bounds__(256) void gemm2(const unsigned short* __restrict__ A,
                                             const unsigned short* __restrict__ Bt0,
                                             const unsigned short* __restrict__ Bt1,
                                             void* __restrict__ C0,
                                             void* __restrict__ C1,
                                             int M, int N, int K, int nsplit) {
  constexpr int IM = BMT / 32, JN = BNT / 32;
  constexpr int NLD = BMT / 64 + BNT / 64;   // per-wave loads per k-tile
  __shared__ __align__(16) unsigned short As[2 * BMT * 32];
  __shared__ __align__(16) unsigned short Bs[2 * BNT * 32];

  const int tid  = threadIdx.x;
  const int w    = tid >> 6;
  const int lane = tid & 63;
  const int lo   = lane & 15;
  const int g    = lane >> 4;
  const int wr   = w >> 1, wc = w & 1;
  const int row0  = blockIdx.x * BMT;   // M on x (fastest) for XCD locality
  const int col0g = blockIdx.y * BNT;
  const bool second = (col0g >= nsplit);            // block-uniform
  const unsigned short* Btp = second ? Bt1 : Bt0;
  const int col0 = second ? col0g - nsplit : col0g;

  floatx4 acc[IM][JN];
#pragma unroll
  for (int i = 0; i < IM; ++i)
#pragma unroll
    for (int j = 0; j < JN; ++j) acc[i][j] = (floatx4){0.f, 0.f, 0.f, 0.f};

  const int sr = tid >> 2;   // staging row (64 rows per inst)
  const int sc = tid & 3;    // staging k-chunk

  auto stage = [&](int buf, int k0) {
#pragma unroll
    for (int inst = 0; inst < BMT / 64; ++inst) {
      const int r  = inst * 64 + sr;
      const int cs = sc ^ ((r >> 1) & 3);
      load_lds16(A + (size_t)(row0 + r) * K + k0 + cs * 8,
                 As + buf * (BMT * 32) + inst * 2048 + w * 512);
    }
#pragma unroll
    for (int inst = 0; inst < BNT / 64; ++inst) {
      const int r  = inst * 64 + sr;
      const int cs = sc ^ ((r >> 1) & 3);
      load_lds16(Btp + (size_t)(col0 + r) * K + k0 + cs * 8,
                 Bs + buf * (BNT * 32) + inst * 2048 + w * 512);
    }
  };

  const int nk = K / 32;
  stage(0, 0);                          // prologue
  for (int it = 0; it < nk; ++it) {
    const int cur = it & 1;
    if (it + 1 < nk) {
      stage(cur ^ 1, (it + 1) * 32);    // prefetch BEFORE waiting
      waitcnt_vm<NLD>();                // only tile-it's loads
    } else {
      waitcnt_vm<0>();
    }
    asm volatile("s_barrier" ::: "memory");

    const unsigned short* Ac = As + cur * (BMT * 32);
    const unsigned short* Bc = Bs + cur * (BNT * 32);
    short8 af[IM], bf[JN];
#pragma unroll
    for (int i = 0; i < IM; ++i) {
      const int rm = (BMT / 2) * wr + 16 * i + lo;
      af[i] = *(const short8*)(Ac + rm * 32 + ((g ^ ((rm >> 1) & 3)) * 8));
    }
#pragma unroll
    for (int j = 0; j < JN; ++j) {
      const int rn = (BNT / 2) * wc + 16 * j + lo;
      bf[j] = *(const short8*)(Bc + rn * 32 + ((g ^ ((rn >> 1) & 3)) * 8));
    }
#pragma unroll
    for (int i = 0; i < IM; ++i)
#pragma unroll
      for (int j = 0; j < JN; ++j)
        acc[i][j] = __builtin_amdgcn_mfma_f32_16x16x32_bf16(af[i], bf[j], acc[i][j], 0, 0, 0);

    asm volatile("s_barrier" ::: "memory");  // cur buf free for it+2 prefetch
  }

#pragma unroll
  for (int i = 0; i < IM; ++i) {
    const int mbase = row0 + (BMT / 2) * wr + 16 * i + g * 4;
#pragma unroll
    for (int j = 0; j < JN; ++j) {
      const int nl = col0 + (BNT / 2) * wc + 16 * j + lo;
      const int bq = mbase >> 11, hh = nl >> 6, d = nl & 63;
      if (KIND == 2 && second) {
        const int l = mbase & 2047;
        uint2 o;
        o.x = pk_bf16(acc[i][j][0], acc[i][j][1]);
        o.y = pk_bf16(acc[i][j][2], acc[i][j][3]);
        *(uint2*)(&((unsigned short*)C1)[((size_t)(bq * HH + hh) * HDD + d) * LL + l]) = o;
      } else {
#pragma unroll
        for (int r = 0; r < 4; ++r) {
          const float v = acc[i][j][r];
          const int mm = mbase + r;
          const int l = mm & 2047;
          if (KIND == 0) {
            ((float*)C0)[(size_t)mm * N + nl] = v;
          } else if (KIND == 1) {
            if (!second)
              ((unsigned short*)C0)[((size_t)(bq * HH + hh) * LL + l) * HDD + d] = f2bf(v);
            else
              ((unsigned short*)C1)[(size_t)mm * LDIM + nl] = f2bf(v);
          } else {
            ((unsigned short*)C0)[((size_t)(bq * HH + hh) * LL + l) * HDD + d] = f2bf(v);
          }
        }
      }
    }
  }
}

// ---------------------------------------------------------------------------
// MFMA causal flash attention v8: merged-pair streaming + 3-deep pipeline.
//   Qh,Kh bf16 [B][H][L][64]; Vt bf16 [B][H][64][L]; y bf16 [B*L][1024].
// Block (h, b, pair): pair p owns q-tiles qtH=31-p and qtL=p; ONE k-loop
// over tiles 0..qtH, each staged tile feeds qtH always + qtL when it<=qtL
// (every tile fetched once, 33 compute units/block, balanced).
// 3 K/V LDS buffers, prefetch 2 tiles ahead, steady-state vmcnt(8): the DMA
// gets ~2 compute-iterations to land (v7's 1-deep prefetch exposed latency).
// Grid h-fastest: one head's blocks share an XCD -> K/V stays in its L2.
// ---------------------------------------------------------------------------
#define SC2 0.18033688011112042f   // 0.125 * log2(e)

__global__ __launch_bounds__(256) void flash_mfma8(const unsigned short* __restrict__ Qh,
                                                   const unsigned short* __restrict__ Kh,
                                                   const unsigned short* __restrict__ Vt,
                                                   unsigned short* __restrict__ y) {
  const int w    = threadIdx.x >> 6;
  const int lane = threadIdx.x & 63;
  const int lo   = lane & 15;
  const int g    = lane >> 4;
  const int h    = blockIdx.x;
  const int b    = blockIdx.y;
  const int pair = blockIdx.z;     // 0..15
  const int qtH  = 31 - pair;
  const int qtL  = pair;

  __shared__ __align__(16) unsigned short Ks[3 * 64 * 64];  // [buf][k][d] swiz
  __shared__ __align__(16) unsigned short Vs[3 * 64 * 64];  // [buf][d][k] swiz
  __shared__ __align__(16) unsigned short Pq[4][16 * 64];   // per-wave [q][k]

  const size_t bh = (size_t)(b * HH + h);
  const unsigned short* Qp = Qh + bh * LL * HDD;
  const unsigned short* Kp = Kh + bh * LL * HDD;
  const unsigned short* Vp = Vt + bh * (size_t)HDD * LL;
  unsigned short* Pw = Pq[w];

  const int qHw = qtH * 64 + w * 16;   // this wave's heavy queries
  const int qLw = qtL * 64 + w * 16;   // this wave's light queries

  // Q B-frags for both q-tiles: B[d=c*32+g*8+j][q=lo]
  short8 qfH0 = *(const short8*)(Qp + (size_t)(qHw + lo) * HDD + g * 8);
  short8 qfH1 = *(const short8*)(Qp + (size_t)(qHw + lo) * HDD + 32 + g * 8);
  short8 qfL0 = *(const short8*)(Qp + (size_t)(qLw + lo) * HDD + g * 8);
  short8 qfL1 = *(const short8*)(Qp + (size_t)(qLw + lo) * HDD + 32 + g * 8);

  floatx4 otH[4], otL[4];
#pragma unroll
  for (int ds = 0; ds < 4; ++ds) {
    otH[ds] = (floatx4){0.f, 0.f, 0.f, 0.f};
    otL[ds] = (floatx4){0.f, 0.f, 0.f, 0.f};
  }
  float lsumH = 0.f, lsumL = 0.f;

  const int srow = lane >> 3;   // staging: 8 rows/inst
  const int sch  = lane & 7;

  auto stage = [&](int buf, int k0) {
#pragma unroll
    for (int t = 0; t < 2; ++t) {
      const int rbase = w * 16 + t * 8;
      const int row   = rbase + srow;
      const int cs    = sch ^ (row & 7);
      load_lds16(Kp + (size_t)(k0 + row) * HDD + cs * 8, Ks + buf * 4096 + rbase * 64);
      load_lds16(Vp + (size_t)row * LL + k0 + cs * 8,    Vs + buf * 4096 + rbase * 64);
    }
  };

  // one q-tile's work against the staged 64-key tile
  auto tile_qt = [&](const unsigned short* Kc, const unsigned short* Vc,
                     short8 qf0, short8 qf1, floatx4* ot, float& lsum,
                     int qw, int k0, bool masked) {
    // ---- St(64k x 16q) = K Q^T ----
    floatx4 st[4];
#pragma unroll
    for (int ks = 0; ks < 4; ++ks) {
      const int rm = ks * 16 + lo;
      short8 a0 = *(const short8*)(Kc + rm * 64 + ((g ^ (rm & 7)) * 8));
      short8 a1 = *(const short8*)(Kc + rm * 64 + (((4 + g) ^ (rm & 7)) * 8));
      floatx4 s = (floatx4){0.f, 0.f, 0.f, 0.f};
      s = __builtin_amdgcn_mfma_f32_16x16x32_bf16(a0, qf0, s, 0, 0, 0);
      s = __builtin_amdgcn_mfma_f32_16x16x32_bf16(a1, qf1, s, 0, 0, 0);
      st[ks] = s;
    }
    // ---- fixed-max softmax + P^T -> per-wave LDS [q][k] (swizzled) ----
    if (!masked) {
#pragma unroll
      for (int ks = 0; ks < 4; ++ks) {
        float p[4];
#pragma unroll
        for (int r = 0; r < 4; ++r) {
          p[r] = __builtin_amdgcn_exp2f(st[ks][r] * SC2);
          lsum += p[r];
        }
        uint2 w2;
        w2.x = pk_bf16(p[0], p[1]);
        w2.y = pk_bf16(p[2], p[3]);
        *(uint2*)(Pw + lo * 64 + (((ks * 2 + (g >> 1)) ^ (lo & 7)) * 8) + (g & 1) * 4) = w2;
      }
    } else {
      const int qq = qw + lo;
#pragma unroll
      for (int ks = 0; ks < 4; ++ks) {
        float p[4];
#pragma unroll
        for (int r = 0; r < 4; ++r) {
          const int kk = k0 + ks * 16 + g * 4 + r;
          const float e = __builtin_amdgcn_exp2f(st[ks][r] * SC2);
          p[r] = (kk <= qq) ? e : 0.f;
          lsum += p[r];
        }
        uint2 w2;
        w2.x = pk_bf16(p[0], p[1]);
        w2.y = pk_bf16(p[2], p[3]);
        *(uint2*)(Pw + lo * 64 + (((ks * 2 + (g >> 1)) ^ (lo & 7)) * 8) + (g & 1) * 4) = w2;
      }
    }
    // ---- O^T(64d x 16q) += V^T P^T ----
    short8 pf0 = *(const short8*)(Pw + lo * 64 + ((g ^ (lo & 7)) * 8));
    short8 pf1 = *(const short8*)(Pw + lo * 64 + (((4 + g) ^ (lo & 7)) * 8));
#pragma unroll
    for (int ds = 0; ds < 4; ++ds) {
      const int rm = ds * 16 + lo;
      short8 v0 = *(const short8*)(Vc + rm * 64 + ((g ^ (rm & 7)) * 8));
      short8 v1 = *(const short8*)(Vc + rm * 64 + (((4 + g) ^ (rm & 7)) * 8));
      ot[ds] = __builtin_amdgcn_mfma_f32_16x16x32_bf16(v0, pf0, ot[ds], 0, 0, 0);
      ot[ds] = __builtin_amdgcn_mfma_f32_16x16x32_bf16(v1, pf1, ot[ds], 0, 0, 0);
    }
  };

  const int ntiles = qtH + 1;     // >= 17 always
  stage(0, 0);                    // prologue: 2 tiles in flight
  stage(1, 64);
  for (int it = 0; it < ntiles; ++it) {
    const int cur = it % 3;
    const int k0  = it * 64;
    if (it + 2 < ntiles) {
      stage((it + 2) % 3, k0 + 128);   // keep 2 tiles in flight
      waitcnt_vm<8>();                 // drain only tile-it's 4 loads
    } else if (it + 1 < ntiles) {
      waitcnt_vm<4>();
    } else {
      waitcnt_vm<0>();
    }
    asm volatile("s_barrier" ::: "memory");

    const unsigned short* Kc = Ks + cur * 4096;
    const unsigned short* Vc = Vs + cur * 4096;

    tile_qt(Kc, Vc, qfH0, qfH1, otH, lsumH, qHw, k0, it == qtH);
    if (it <= qtL)   // block-uniform
      tile_qt(Kc, Vc, qfL0, qfL1, otL, lsumL, qLw, k0, it == qtL);

    asm volatile("s_barrier" ::: "memory");  // cur buf free for it+3 prefetch
  }

  // epilogue: reduce l over g-groups, write both q-tiles
  auto finish = [&](floatx4* ot, float lsum, int qw) {
    float s = lsum;
    s += __shfl_xor(s, 16);
    s += __shfl_xor(s, 32);
    const float inv = 1.0f / s;
#pragma unroll
    for (int ds = 0; ds < 4; ++ds) {
      uint2 o;
      o.x = pk_bf16(ot[ds][0] * inv, ot[ds][1] * inv);
      o.y = pk_bf16(ot[ds][2] * inv, ot[ds][3] * inv);
      *(uint2*)(y + (size_t)(b * LL + qw + lo) * (HH * HDD) + h * HDD + ds * 16 + g * 4) = o;
    }
  };
  finish(otH, lsumH, qHw);
  finish(otL, lsumL, qLw);
}

// ---------------------------------------------------------------------------
// Launch
// ---------------------------------------------------------------------------
extern "C" void kernel_launch(void* const* d_in, const int* in_sizes, int n_in,
                              void* d_out, int out_size, void* d_ws, size_t ws_size,
                              hipStream_t stream) {
  const float* x   = (const float*)d_in[0];  // [4096][1024]
  const float* Wq  = (const float*)d_in[1];  // [1024][1024]
  const float* Wkv = (const float*)d_in[2];  // [1024][256]
  const float* Wku = (const float*)d_in[3];  // [256][1024]
  const float* Wvu = (const float*)d_in[4];  // [256][1024]
  const float* Wo  = (const float*)d_in[5];  // [1024][1024]
  float* out = (float*)d_out;                // [4096][1024] fp32

  // workspace (bf16 elements)
  unsigned short* xb     = (unsigned short*)d_ws;          // 4096x1024
  unsigned short* WqT    = xb + (size_t)MTOT * DD;         // 1024x1024 [N][K]
  unsigned short* WkvT   = WqT + 1024 * 1024;              // 256x1024
  unsigned short* WkuT   = WkvT + 256 * 1024;              // 1024x256
  unsigned short* WvuT   = WkuT + 1024 * 256;              // 1024x256
  unsigned short* WoT    = WvuT + 1024 * 256;              // 1024x1024
  unsigned short* latent = WoT + 1024 * 1024;              // 4096x256
  unsigned short* Qh     = latent + (size_t)MTOT * LDIM;   // 4096x1024
  unsigned short* Kh     = Qh + (size_t)MTOT * DD;
  unsigned short* Vt     = Kh + (size_t)MTOT * DD;
  unsigned short* y      = Vt + (size_t)MTOT * DD;

  // prep
  cast_bf16<<<dim3(MTOT * DD / 1024), dim3(256), 0, stream>>>(x, xb, MTOT * DD / 4);
  transpose_cast5<<<dim3(32, 32, 5), dim3(32, 8), 0, stream>>>(
      Wq, Wkv, Wku, Wvu, Wo, WqT, WkvT, WkuT, WvuT, WoT);

  // fused Q + latent:  [4096,1024] x [1024, 1024+256]   (128x64 tiles, 640 blocks)
  gemm2<1, 128, 64><<<dim3(MTOT / 128, 1280 / 64), dim3(256), 0, stream>>>(
      xb, WqT, WkvT, Qh, latent, MTOT, 1280, DD, 1024);
  // fused K + V:       [4096,256] x [256, 1024+1024]    (128x128 tiles, 512 blocks)
  gemm2<2, 128, 128><<<dim3(MTOT / 128, 2048 / 128), dim3(256), 0, stream>>>(
      latent, WkuT, WvuT, Kh, Vt, MTOT, 2048, LDIM, 1024);

  // attention (merged-pair flash, 3-deep pipeline; h fastest for XCD L2)
  flash_mfma8<<<dim3(HH, BB, 16), dim3(256), 0, stream>>>(Qh, Kh, Vt, y);

  // output projection (fp32 out; 128x64 tiles, 512 blocks)
  gemm2<0, 128, 64><<<dim3(MTOT / 128, DD / 64), dim3(256), 0, stream>>>(
      y, WoT, nullptr, out, nullptr, MTOT, DD, DD, DD);
}

// Round 11
// 167.201 us; speedup vs baseline: 1.1003x; 1.0186x over previous
//
#include <hip/hip_runtime.h>
#include <hip/hip_bf16.h>

// Problem constants (reference: B=2, L=2048, D=1024, H=16, HD=64, LD=256)
#define BB   2
#define LL   2048
#define DD   1024
#define HH   16
#define HDD  64
#define LDIM 256
#define MTOT (BB * LL)   // 4096 rows for all projection GEMMs

using short8  = __attribute__((ext_vector_type(8))) short;  // 8 bf16 (4 VGPRs)
using floatx4 = __attribute__((ext_vector_type(4))) float;  // MFMA C/D frag

static __device__ __forceinline__ unsigned short f2bf(float x) {
  __hip_bfloat16 h = __float2bfloat16(x);
  return *reinterpret_cast<unsigned short*>(&h);
}
static __device__ __forceinline__ unsigned int pk_bf16(float a, float b) {
  return (unsigned int)f2bf(a) | ((unsigned int)f2bf(b) << 16);
}
// async 16B/lane global->LDS; lds base wave-uniform, HW adds lane*16
static __device__ __forceinline__ void load_lds16(const unsigned short* g,
                                                  unsigned short* l) {
  __builtin_amdgcn_global_load_lds(
      (const __attribute__((address_space(1))) unsigned int*)g,
      (__attribute__((address_space(3))) unsigned int*)l, 16, 0, 0);
}
template <int N>
static __device__ __forceinline__ void waitcnt_vm() {
  if constexpr (N == 0) asm volatile("s_waitcnt vmcnt(0)" ::: "memory");
  else if constexpr (N == 4) asm volatile("s_waitcnt vmcnt(4)" ::: "memory");
  else if constexpr (N == 6) asm volatile("s_waitcnt vmcnt(6)" ::: "memory");
  else if constexpr (N == 8) asm volatile("s_waitcnt vmcnt(8)" ::: "memory");
}
// End-of-pipelined-iteration barrier. MUST drain this wave's LDS reads
// (lgkmcnt) BEFORE the barrier: after the barrier another wave re-stages
// the buffer via DMA, and a still-queued ds_read would see the new data
// (the R10 post-timing divergence). ISA rule: "s_barrier (s_waitcnt first
// if data dep!)".
static __device__ __forceinline__ void lds_drain_barrier() {
  asm volatile("s_waitcnt lgkmcnt(0)\n\ts_barrier" ::: "memory");
}

// ---------------------------------------------------------------------------
// cast fp32 -> bf16, 4 elems/thread
// ---------------------------------------------------------------------------
__global__ __launch_bounds__(256) void cast_bf16(const float* __restrict__ in,
                                                 unsigned short* __restrict__ out,
                                                 int n4) {
  const int i = (blockIdx.x * 256 + threadIdx.x);
  if (i < n4) {
    float4 v = ((const float4*)in)[i];
    ushort4 o;
    o.x = f2bf(v.x); o.y = f2bf(v.y); o.z = f2bf(v.z); o.w = f2bf(v.w);
    ((ushort4*)out)[i] = o;
  }
}

// ---------------------------------------------------------------------------
// fused transpose+cast for all 5 weights: fp32 [R][C] -> bf16 [C][R].
// grid (32,32,5), block (32,8); out-of-range tiles exit early.
// ---------------------------------------------------------------------------
__global__ __launch_bounds__(256) void transpose_cast5(
    const float* __restrict__ Wq, const float* __restrict__ Wkv,
    const float* __restrict__ Wku, const float* __restrict__ Wvu,
    const float* __restrict__ Wo,
    unsigned short* __restrict__ WqT, unsigned short* __restrict__ WkvT,
    unsigned short* __restrict__ WkuT, unsigned short* __restrict__ WvuT,
    unsigned short* __restrict__ WoT) {
  const float* src; unsigned short* dst; int R, C;
  switch (blockIdx.z) {
    case 0:  src = Wq;  dst = WqT;  R = 1024; C = 1024; break;
    case 1:  src = Wkv; dst = WkvT; R = 1024; C = 256;  break;
    case 2:  src = Wku; dst = WkuT; R = 256;  C = 1024; break;
    case 3:  src = Wvu; dst = WvuT; R = 256;  C = 1024; break;
    default: src = Wo;  dst = WoT;  R = 1024; C = 1024; break;
  }
  if ((int)blockIdx.x * 32 >= C || (int)blockIdx.y * 32 >= R) return;

  __shared__ float tile[32][33];
  const int tx = threadIdx.x, ty = threadIdx.y;
#pragma unroll
  for (int i = 0; i < 4; ++i) {
    const int r = blockIdx.y * 32 + ty + i * 8;
    tile[ty + i * 8][tx] = src[(size_t)r * C + blockIdx.x * 32 + tx];
  }
  __syncthreads();
#pragma unroll
  for (int i = 0; i < 4; ++i) {
    const int c = blockIdx.x * 32 + ty + i * 8;
    dst[(size_t)c * R + blockIdx.y * 32 + tx] = f2bf(tile[tx][ty + i * 8]);
  }
}

// ---------------------------------------------------------------------------
// bf16 MFMA GEMM, pipelined K-loop: C = A[M,K] * Bt[N,K]^T.
// Grid (x = M-tiles [fastest], y = N-tiles) for XCD L2 locality on A.
// Tile BMT x BNT, BKT in {32,64}, 256 thr = 4 waves (2x2). Double-buffered
// global_load_lds staging; prefetch k+1 BEFORE waiting, vmcnt(NLD) + raw
// s_barrier (never vmcnt(0) mid-loop); end-of-iter lds_drain_barrier closes
// the ds_read vs re-stage DMA race. BKT=64 halves barrier count.
// KIND 0: fp32 C0[M][N]
// KIND 1: C0 = Qh bf16 [B][H][L][64], C1 = latent bf16 [M][256]
// KIND 2: C0 = Kh bf16 [B][H][L][64], C1 = Vt bf16 [B][H][64][L] (packed st.)
// ---------------------------------------------------------------------------
template <int KIND, int BMT, int BNT, int BKT>
__global__ __launch_bounds__(256) void gemm2(const unsigned short* __restrict__ A,
                                             const unsigned short* __restrict__ Bt0,
                                             const unsigned short* __restrict__ Bt1,
                                             void* __restrict__ C0,
                                             void* __restrict__ C1,
                                             int M, int N, int K, int nsplit) {
  constexpr int IM = BMT / 32, JN = BNT / 32;
  constexpr int TA = BMT * BKT, TB = BNT * BKT;     // elems per staged tile
  constexpr int NIA = TA / 2048, NIB = TB / 2048;   // 2048 elems per inst
  constexpr int NLD = NIA + NIB;                    // per-wave loads per k-tile
  constexpr int RPI = 2048 / BKT;                   // rows per inst (64 or 32)
  __shared__ __align__(16) unsigned short As[2 * TA];
  __shared__ __align__(16) unsigned short Bs[2 * TB];

  const int tid  = threadIdx.x;
  const int w    = tid >> 6;
  const int lane = tid & 63;
  const int lo   = lane & 15;
  const int g    = lane >> 4;
  const int wr   = w >> 1, wc = w & 1;
  const int row0  = blockIdx.x * BMT;   // M on x (fastest) for XCD locality
  const int col0g = blockIdx.y * BNT;
  const bool second = (col0g >= nsplit);            // block-uniform
  const unsigned short* Btp = second ? Bt1 : Bt0;
  const int col0 = second ? col0g - nsplit : col0g;

  floatx4 acc[IM][JN];
#pragma unroll
  for (int i = 0; i < IM; ++i)
#pragma unroll
    for (int j = 0; j < JN; ++j) acc[i][j] = (floatx4){0.f, 0.f, 0.f, 0.f};

  // staging thread -> (row within inst, k-chunk of 8)
  const int sr = (BKT == 32) ? (tid >> 2) : (tid >> 3);
  const int sc = (BKT == 32) ? (tid & 3) : (tid & 7);

  auto swz = [](int chunk, int row) {
    if constexpr (BKT == 32) return chunk ^ ((row >> 1) & 3);
    else                     return chunk ^ (row & 7);
  };

  auto stage = [&](int buf, int k0) {
#pragma unroll
    for (int inst = 0; inst < NIA; ++inst) {
      const int r  = inst * RPI + sr;
      const int cs = swz(sc, r);
      load_lds16(A + (size_t)(row0 + r) * K + k0 + cs * 8,
                 As + buf * TA + inst * 2048 + w * 512);
    }
#pragma unroll
    for (int inst = 0; inst < NIB; ++inst) {
      const int r  = inst * RPI + sr;
      const int cs = swz(sc, r);
      load_lds16(Btp + (size_t)(col0 + r) * K + k0 + cs * 8,
                 Bs + buf * TB + inst * 2048 + w * 512);
    }
  };

  const int nk = K / BKT;
  stage(0, 0);                          // prologue
  for (int it = 0; it < nk; ++it) {
    const int cur = it & 1;
    if (it + 1 < nk) {
      stage(cur ^ 1, (it + 1) * BKT);   // prefetch BEFORE waiting
      waitcnt_vm<NLD>();                // only tile-it's loads
    } else {
      waitcnt_vm<0>();
    }
    asm volatile("s_barrier" ::: "memory");

    const unsigned short* Ac = As + cur * TA;
    const unsigned short* Bc = Bs + cur * TB;
#pragma unroll
    for (int kk = 0; kk < BKT / 32; ++kk) {   // sequential kk: caps VGPRs
      short8 af[IM], bf[JN];
#pragma unroll
      for (int i = 0; i < IM; ++i) {
        const int rm = (BMT / 2) * wr + 16 * i + lo;
        af[i] = *(const short8*)(Ac + (size_t)rm * BKT + swz(kk * 4 + g, rm) * 8);
      }
#pragma unroll
      for (int j = 0; j < JN; ++j) {
        const int rn = (BNT / 2) * wc + 16 * j + lo;
        bf[j] = *(const short8*)(Bc + (size_t)rn * BKT + swz(kk * 4 + g, rn) * 8);
      }
#pragma unroll
      for (int i = 0; i < IM; ++i)
#pragma unroll
        for (int j = 0; j < JN; ++j)
          acc[i][j] = __builtin_amdgcn_mfma_f32_16x16x32_bf16(af[i], bf[j], acc[i][j], 0, 0, 0);
    }

    lds_drain_barrier();   // reads done -> cur buf safe for it+2 prefetch
  }

#pragma unroll
  for (int i = 0; i < IM; ++i) {
    const int mbase = row0 + (BMT / 2) * wr + 16 * i + g * 4;
#pragma unroll
    for (int j = 0; j < JN; ++j) {
      const int nl = col0 + (BNT / 2) * wc + 16 * j + lo;
      const int bq = mbase >> 11, hh = nl >> 6, d = nl & 63;
      if (KIND == 2 && second) {
        const int l = mbase & 2047;
        uint2 o;
        o.x = pk_bf16(acc[i][j][0], acc[i][j][1]);
        o.y = pk_bf16(acc[i][j][2], acc[i][j][3]);
        *(uint2*)(&((unsigned short*)C1)[((size_t)(bq * HH + hh) * HDD + d) * LL + l]) = o;
      } else {
#pragma unroll
        for (int r = 0; r < 4; ++r) {
          const float v = acc[i][j][r];
          const int mm = mbase + r;
          const int l = mm & 2047;
          if (KIND == 0) {
            ((float*)C0)[(size_t)mm * N + nl] = v;
          } else if (KIND == 1) {
            if (!second)
              ((unsigned short*)C0)[((size_t)(bq * HH + hh) * LL + l) * HDD + d] = f2bf(v);
            else
              ((unsigned short*)C1)[(size_t)mm * LDIM + nl] = f2bf(v);
          } else {
            ((unsigned short*)C0)[((size_t)(bq * HH + hh) * LL + l) * HDD + d] = f2bf(v);
          }
        }
      }
    }
  }
}

// ---------------------------------------------------------------------------
// MFMA causal flash attention v9r: merged-pair streaming + 3-deep pipeline
// + per-tile P buffers, phase-interleaved H/L body. End-of-iter
// lds_drain_barrier closes the ds_read vs buffer re-stage race (R10 bug).
//   Qh,Kh bf16 [B][H][L][64]; Vt bf16 [B][H][64][L]; y bf16 [B*L][1024].
// ---------------------------------------------------------------------------
#define SC2 0.18033688011112042f   // 0.125 * log2(e)

__global__ __launch_bounds__(256) void flash_mfma9(const unsigned short* __restrict__ Qh,
                                                   const unsigned short* __restrict__ Kh,
                                                   const unsigned short* __restrict__ Vt,
                                                   unsigned short* __restrict__ y) {
  const int w    = threadIdx.x >> 6;
  const int lane = threadIdx.x & 63;
  const int lo   = lane & 15;
  const int g    = lane >> 4;
  const int h    = blockIdx.x;
  const int b    = blockIdx.y;
  const int pair = blockIdx.z;     // 0..15
  const int qtH  = 31 - pair;
  const int qtL  = pair;

  __shared__ __align__(16) unsigned short Ks[3 * 64 * 64];     // [buf][k][d] swiz
  __shared__ __align__(16) unsigned short Vs[3 * 64 * 64];     // [buf][d][k] swiz
  __shared__ __align__(16) unsigned short Pq[4][2][16 * 64];   // [wave][H/L][q][k]

  const size_t bh = (size_t)(b * HH + h);
  const unsigned short* Qp = Qh + bh * LL * HDD;
  const unsigned short* Kp = Kh + bh * LL * HDD;
  const unsigned short* Vp = Vt + bh * (size_t)HDD * LL;
  unsigned short* PwH = Pq[w][0];
  unsigned short* PwL = Pq[w][1];

  const int qHw = qtH * 64 + w * 16;   // this wave's heavy queries
  const int qLw = qtL * 64 + w * 16;   // this wave's light queries

  // Q B-frags for both q-tiles: B[d=c*32+g*8+j][q=lo]
  short8 qfH0 = *(const short8*)(Qp + (size_t)(qHw + lo) * HDD + g * 8);
  short8 qfH1 = *(const short8*)(Qp + (size_t)(qHw + lo) * HDD + 32 + g * 8);
  short8 qfL0 = *(const short8*)(Qp + (size_t)(qLw + lo) * HDD + g * 8);
  short8 qfL1 = *(const short8*)(Qp + (size_t)(qLw + lo) * HDD + 32 + g * 8);

  floatx4 otH[4], otL[4];
#pragma unroll
  for (int ds = 0; ds < 4; ++ds) {
    otH[ds] = (floatx4){0.f, 0.f, 0.f, 0.f};
    otL[ds] = (floatx4){0.f, 0.f, 0.f, 0.f};
  }
  float lsumH = 0.f, lsumL = 0.f;

  const int srow = lane >> 3;   // staging: 8 rows/inst
  const int sch  = lane & 7;

  auto stage = [&](int buf, int k0) {
#pragma unroll
    for (int t = 0; t < 2; ++t) {
      const int rbase = w * 16 + t * 8;
      const int row   = rbase + srow;
      const int cs    = sch ^ (row & 7);
      load_lds16(Kp + (size_t)(k0 + row) * HDD + cs * 8, Ks + buf * 4096 + rbase * 64);
      load_lds16(Vp + (size_t)row * LL + k0 + cs * 8,    Vs + buf * 4096 + rbase * 64);
    }
  };

  // phase helpers
  auto qk = [&](const unsigned short* Kc, short8 q0f, short8 q1f, floatx4* st) {
#pragma unroll
    for (int ks = 0; ks < 4; ++ks) {
      const int rm = ks * 16 + lo;
      short8 a0 = *(const short8*)(Kc + rm * 64 + ((g ^ (rm & 7)) * 8));
      short8 a1 = *(const short8*)(Kc + rm * 64 + (((4 + g) ^ (rm & 7)) * 8));
      floatx4 s = (floatx4){0.f, 0.f, 0.f, 0.f};
      s = __builtin_amdgcn_mfma_f32_16x16x32_bf16(a0, q0f, s, 0, 0, 0);
      s = __builtin_amdgcn_mfma_f32_16x16x32_bf16(a1, q1f, s, 0, 0, 0);
      st[ks] = s;
    }
  };
  auto sm = [&](floatx4* st, unsigned short* P, float& lsum, int qw, int k0,
                bool masked) {
    if (!masked) {
#pragma unroll
      for (int ks = 0; ks < 4; ++ks) {
        float p[4];
#pragma unroll
        for (int r = 0; r < 4; ++r) {
          p[r] = __builtin_amdgcn_exp2f(st[ks][r] * SC2);
          lsum += p[r];
        }
        uint2 w2;
        w2.x = pk_bf16(p[0], p[1]);
        w2.y = pk_bf16(p[2], p[3]);
        *(uint2*)(P + lo * 64 + (((ks * 2 + (g >> 1)) ^ (lo & 7)) * 8) + (g & 1) * 4) = w2;
      }
    } else {
      const int qq = qw + lo;
#pragma unroll
      for (int ks = 0; ks < 4; ++ks) {
        float p[4];
#pragma unroll
        for (int r = 0; r < 4; ++r) {
          const int kk = k0 + ks * 16 + g * 4 + r;
          const float e = __builtin_amdgcn_exp2f(st[ks][r] * SC2);
          p[r] = (kk <= qq) ? e : 0.f;
          lsum += p[r];
        }
        uint2 w2;
        w2.x = pk_bf16(p[0], p[1]);
        w2.y = pk_bf16(p[2], p[3]);
        *(uint2*)(P + lo * 64 + (((ks * 2 + (g >> 1)) ^ (lo & 7)) * 8) + (g & 1) * 4) = w2;
      }
    }
  };
  auto pv = [&](const unsigned short* Vc, const unsigned short* P, floatx4* ot) {
    short8 pf0 = *(const short8*)(P + lo * 64 + ((g ^ (lo & 7)) * 8));
    short8 pf1 = *(const short8*)(P + lo * 64 + (((4 + g) ^ (lo & 7)) * 8));
#pragma unroll
    for (int ds = 0; ds < 4; ++ds) {
      const int rm = ds * 16 + lo;
      short8 v0 = *(const short8*)(Vc + rm * 64 + ((g ^ (rm & 7)) * 8));
      short8 v1 = *(const short8*)(Vc + rm * 64 + (((4 + g) ^ (rm & 7)) * 8));
      ot[ds] = __builtin_amdgcn_mfma_f32_16x16x32_bf16(v0, pf0, ot[ds], 0, 0, 0);
      ot[ds] = __builtin_amdgcn_mfma_f32_16x16x32_bf16(v1, pf1, ot[ds], 0, 0, 0);
    }
  };

  const int ntiles = qtH + 1;     // >= 17 always
  stage(0, 0);                    // prologue: 2 tiles in flight
  stage(1, 64);
  for (int it = 0; it < ntiles; ++it) {
    const int cur = it % 3;
    const int k0  = it * 64;
    if (it + 2 < ntiles) {
      stage((it + 2) % 3, k0 + 128);   // keep 2 tiles in flight
      waitcnt_vm<8>();                 // drain only tile-it's 4 loads
    } else if (it + 1 < ntiles) {
      waitcnt_vm<4>();
    } else {
      waitcnt_vm<0>();
    }
    asm volatile("s_barrier" ::: "memory");

    const unsigned short* Kc = Ks + cur * 4096;
    const unsigned short* Vc = Vs + cur * 4096;
    const bool doL = (it <= qtL);       // block-uniform

    floatx4 stH[4], stL[4];
    qk(Kc, qfH0, qfH1, stH);
    if (doL) qk(Kc, qfL0, qfL1, stL);
    sm(stH, PwH, lsumH, qHw, k0, it == qtH);
    if (doL) sm(stL, PwL, lsumL, qLw, k0, it == qtL);
    pv(Vc, PwH, otH);
    if (doL) pv(Vc, PwL, otL);

    lds_drain_barrier();   // reads done -> cur buf safe for it+3 prefetch
  }

  // epilogue: reduce l over g-groups, write both q-tiles
  auto finish = [&](floatx4* ot, float lsum, int qw) {
    float s = lsum;
    s += __shfl_xor(s, 16);
    s += __shfl_xor(s, 32);
    const float inv = 1.0f / s;
#pragma unroll
    for (int ds = 0; ds < 4; ++ds) {
      uint2 o;
      o.x = pk_bf16(ot[ds][0] * inv, ot[ds][1] * inv);
      o.y = pk_bf16(ot[ds][2] * inv, ot[ds][3] * inv);
      *(uint2*)(y + (size_t)(b * LL + qw + lo) * (HH * HDD) + h * HDD + ds * 16 + g * 4) = o;
    }
  };
  finish(otH, lsumH, qHw);
  finish(otL, lsumL, qLw);
}

// ---------------------------------------------------------------------------
// Launch
// ---------------------------------------------------------------------------
extern "C" void kernel_launch(void* const* d_in, const int* in_sizes, int n_in,
                              void* d_out, int out_size, void* d_ws, size_t ws_size,
                              hipStream_t stream) {
  const float* x   = (const float*)d_in[0];  // [4096][1024]
  const float* Wq  = (const float*)d_in[1];  // [1024][1024]
  const float* Wkv = (const float*)d_in[2];  // [1024][256]
  const float* Wku = (const float*)d_in[3];  // [256][1024]
  const float* Wvu = (const float*)d_in[4];  // [256][1024]
  const float* Wo  = (const float*)d_in[5];  // [1024][1024]
  float* out = (float*)d_out;                // [4096][1024] fp32

  // workspace (bf16 elements)
  unsigned short* xb     = (unsigned short*)d_ws;          // 4096x1024
  unsigned short* WqT    = xb + (size_t)MTOT * DD;         // 1024x1024 [N][K]
  unsigned short* WkvT   = WqT + 1024 * 1024;              // 256x1024
  unsigned short* WkuT   = WkvT + 256 * 1024;              // 1024x256
  unsigned short* WvuT   = WkuT + 1024 * 256;              // 1024x256
  unsigned short* WoT    = WvuT + 1024 * 256;              // 1024x1024
  unsigned short* latent = WoT + 1024 * 1024;              // 4096x256
  unsigned short* Qh     = latent + (size_t)MTOT * LDIM;   // 4096x1024
  unsigned short* Kh     = Qh + (size_t)MTOT * DD;
  unsigned short* Vt     = Kh + (size_t)MTOT * DD;
  unsigned short* y      = Vt + (size_t)MTOT * DD;

  // prep
  cast_bf16<<<dim3(MTOT * DD / 1024), dim3(256), 0, stream>>>(x, xb, MTOT * DD / 4);
  transpose_cast5<<<dim3(32, 32, 5), dim3(32, 8), 0, stream>>>(
      Wq, Wkv, Wku, Wvu, Wo, WqT, WkvT, WkuT, WvuT, WoT);

  // fused Q + latent:  [4096,1024] x [1024, 1024+256]   (128x64, BK=64)
  gemm2<1, 128, 64, 64><<<dim3(MTOT / 128, 1280 / 64), dim3(256), 0, stream>>>(
      xb, WqT, WkvT, Qh, latent, MTOT, 1280, DD, 1024);
  // fused K + V:       [4096,256] x [256, 1024+1024]    (128x128, BK=32)
  gemm2<2, 128, 128, 32><<<dim3(MTOT / 128, 2048 / 128), dim3(256), 0, stream>>>(
      latent, WkuT, WvuT, Kh, Vt, MTOT, 2048, LDIM, 1024);

  // attention (merged-pair flash v9r; h fastest for XCD L2)
  flash_mfma9<<<dim3(HH, BB, 16), dim3(256), 0, stream>>>(Qh, Kh, Vt, y);

  // output projection (fp32 out; 128x64, BK=64)
  gemm2<0, 128, 64, 64><<<dim3(MTOT / 128, DD / 64), dim3(256), 0, stream>>>(
      y, WoT, nullptr, out, nullptr, MTOT, DD, DD, DD);
}